// Round 1
// baseline (234.805 us; speedup 1.0000x reference)
//
#include <hip/hip_runtime.h>
#include <hip/hip_bf16.h>
#include <stdint.h>

typedef __bf16 bf16;
typedef bf16 bf16x4 __attribute__((ext_vector_type(4)));
typedef bf16 bf16x8 __attribute__((ext_vector_type(8)));
typedef float f32x4 __attribute__((ext_vector_type(4)));
typedef float fv4 __attribute__((ext_vector_type(4)));   // native clang vector for nontemporal builtins

#define FIN   128
#define FOUT  128
#define FANIN 640
#define BM    128
#define BK    64      // K sub-chunk (bf16 elems) -> A/B LDS tiles 16KB each, x2 dbuf = 64KB

__device__ __forceinline__ void async16(const void* g, void* l) {
    __builtin_amdgcn_global_load_lds((const __attribute__((address_space(1))) void*)g,
                                     (__attribute__((address_space(3))) void*)l,
                                     16, 0, 0);
}

// ---------------- convert fp32 -> bf16 (x and W), non-temporal reads ----------------
__global__ __launch_bounds__(256)
void convert_kernel(const float* __restrict__ x, const float* __restrict__ W,
                    bf16* __restrict__ xb, bf16* __restrict__ wb,
                    long nx4, long ntot4)
{
    long i = (long)blockIdx.x * 256 + threadIdx.x;   // float4 index
    if (i >= ntot4) return;
    fv4 v;
    bf16* dst;
    if (i < nx4) { v = __builtin_nontemporal_load((const fv4*)x + i); dst = xb + i * 4; }
    else         { long k = i - nx4;
                   v = __builtin_nontemporal_load((const fv4*)W + k); dst = wb + k * 4; }
    bf16x4 h = { (bf16)v.x, (bf16)v.y, (bf16)v.z, (bf16)v.w };
    *(bf16x4*)dst = h;
}

// ---------------- gather-GEMM v2: double-buffered LDS + counted-vmcnt pipeline ----------------
// K = 10 sub-chunks of 64 (gather slot j = c>>1, half h = c&1).
// T3+T4: stage chunk c+1 into buf^1 while computing chunk c from buf; raw s_barrier with
// s_waitcnt vmcnt(8) (the 8 outstanding = next-chunk loads staying in flight across the
// barrier) instead of __syncthreads()'s vmcnt(0) drain. T5: setprio around MFMA cluster.
// XOR swizzle (16B-chunk ^ row&7) baked into the GLOBAL address of global_load_lds so
// LDS rows stay contiguous yet ds_read_b128 sees only 2-way bank aliasing (free).
// nbr loads drained with vmcnt(0) BEFORE the loop so manual vmcnt counts are exact.
__global__ __launch_bounds__(256)
void mcc_mfma(const bf16* __restrict__ xb, const int* __restrict__ nbr,
              const bf16* __restrict__ wb, const float* __restrict__ bias,
              float* __restrict__ out, int N)
{
    __shared__ __align__(16) bf16 Asm[2][BM][BK];     // 32 KB
    __shared__ __align__(16) bf16 Bsm[2][FOUT][BK];   // 32 KB

    const int tid  = threadIdx.x;
    const int wave = tid >> 6;
    const int lane = tid & 63;
    const int quad = lane >> 4;
    const int l16  = lane & 15;
    const int wr   = wave >> 1;      // wave row 0..1 (64 out-rows each)
    const int wc   = wave & 1;       // wave col 0..1 (64 out-cols each)
    const int m0   = blockIdx.x * BM;

    const int r8 = lane >> 3;        // row-within-staging-instr 0..7
    const int c8 = lane & 7;         // 16B chunk 0..7
    const int sw = (c8 ^ r8) << 4;   // swizzled chunk byte offset

    // preload gather row ids into VGPRs: gsel[i][j], i = staging instr, j = slot
    int gsel[4][5];
    #pragma unroll
    for (int i = 0; i < 4; ++i) {
        int tr   = wave * 32 + i * 8 + r8;
        int node = m0 + tr;
        node = node < N ? node : N - 1;
        gsel[i][0] = node;
        #pragma unroll
        for (int jj = 1; jj < 5; ++jj)
            gsel[i][jj] = nbr[(long)node * 4 + (jj - 1)];   // 8 lanes share addr (broadcast)
    }
    // drain the nbr loads so the only outstanding VMEM ops in the loop are our async16s
    asm volatile("s_waitcnt vmcnt(0)" ::: "memory");

    f32x4 acc[4][4] = {};

    // stage chunk k (j = k>>1, h = k&1) into LDS buffer pb: 4 A + 4 B async16 per wave
    #define STAGE(pb, k) do {                                                              \
        const int j_ = (k) >> 1, h_ = (k) & 1;                                             \
        _Pragma("unroll")                                                                  \
        for (int i = 0; i < 4; ++i) {                                                      \
            const char* ga = (const char*)xb + ((long)gsel[i][j_] << 8) + h_ * 128 + sw;   \
            async16(ga, &Asm[pb][wave * 32 + i * 8][0]);                                   \
        }                                                                                  \
        _Pragma("unroll")                                                                  \
        for (int i = 0; i < 4; ++i) {                                                      \
            int br_ = wave * 32 + i * 8 + r8;                                              \
            const char* gb = (const char*)wb + (long)br_ * (FANIN * 2)                     \
                             + j_ * 256 + h_ * 128 + sw;                                   \
            async16(gb, &Bsm[pb][wave * 32 + i * 8][0]);                                   \
        }                                                                                  \
    } while (0)

    STAGE(0, 0);

    #pragma unroll
    for (int c = 0; c < 10; ++c) {
        const int cur = c & 1;

        if (c < 9) {
            STAGE(cur ^ 1, c + 1);                          // prefetch next chunk
            // wait for current chunk's 8 loads; the 8 just-issued stay in flight
            asm volatile("s_waitcnt vmcnt(8)" ::: "memory");
        } else {
            asm volatile("s_waitcnt vmcnt(0)" ::: "memory"); // last chunk: nothing behind it
        }
        __builtin_amdgcn_s_barrier();                       // all waves' current loads landed
        asm volatile("" ::: "memory");                      // fence: no ds_read hoists above

        #pragma unroll
        for (int s = 0; s < 2; ++s) {
            bf16x8 a[4], b[4];
            #pragma unroll
            for (int mi = 0; mi < 4; ++mi) {
                int ar = wr * 64 + mi * 16 + l16;
                a[mi] = *(const bf16x8*)&Asm[cur][ar][(((s * 4 + quad) ^ (l16 & 7)) << 3)];
            }
            #pragma unroll
            for (int ni = 0; ni < 4; ++ni) {
                int br = wc * 64 + ni * 16 + l16;
                b[ni] = *(const bf16x8*)&Bsm[cur][br][(((s * 4 + quad) ^ (l16 & 7)) << 3)];
            }
            __builtin_amdgcn_s_setprio(1);
            #pragma unroll
            for (int mi = 0; mi < 4; ++mi)
                #pragma unroll
                for (int ni = 0; ni < 4; ++ni)
                    acc[mi][ni] = __builtin_amdgcn_mfma_f32_16x16x32_bf16(
                                      a[mi], b[ni], acc[mi][ni], 0, 0, 0);
            __builtin_amdgcn_s_setprio(0);
        }

        if (c < 9) {
            asm volatile("" ::: "memory");                  // fence: reads done before overwrite
            __builtin_amdgcn_s_barrier();                   // WAR: buf[cur] free for stage(c+2)
        }
    }
    #undef STAGE

    // ---- epilogue: C layout col=lane&15, row=quad*4+reg; non-temporal stores ----
    float bv[4];
    #pragma unroll
    for (int ni = 0; ni < 4; ++ni) bv[ni] = bias[wc * 64 + ni * 16 + l16];

    #pragma unroll
    for (int mi = 0; mi < 4; ++mi) {
        #pragma unroll
        for (int r = 0; r < 4; ++r) {
            int row = m0 + wr * 64 + mi * 16 + quad * 4 + r;
            if (row < N) {
                #pragma unroll
                for (int ni = 0; ni < 4; ++ni) {
                    int n = wc * 64 + ni * 16 + l16;
                    __builtin_nontemporal_store(acc[mi][ni][r] + bv[ni],
                                                &out[(long)row * FOUT + n]);
                }
            }
        }
    }
}

// ---------------- round-1 fallback (used only if ws_size too small) ----------------
#define FBM 64
#define LDA 136
__global__ __launch_bounds__(256)
void mcc_fallback(const float* __restrict__ x, const int* __restrict__ nbr,
                  const float* __restrict__ W, const float* __restrict__ bias,
                  float* __restrict__ out, int N)
{
    __shared__ __align__(16) bf16 As[FBM][LDA];
    __shared__ __align__(16) bf16 Bs[FOUT][LDA];
    const int tid = threadIdx.x;
    const int m0 = blockIdx.x * FBM;
    const int wave = tid >> 6, lane = tid & 63, quad = lane >> 4, l16 = lane & 15;
    f32x4 acc[8] = {};
    const int arow = tid >> 2, asub = tid & 3, brow = tid >> 1, bhalf = tid & 1;
    for (int j = 0; j < 5; ++j) {
        {
            const float4* src = (const float4*)(W + (long)brow * FANIN + j * FIN + bhalf * 64);
            bf16* dst = &Bs[brow][bhalf * 64];
            #pragma unroll
            for (int i = 0; i < 16; ++i) {
                float4 v = src[i];
                dst[i*4+0]=(bf16)v.x; dst[i*4+1]=(bf16)v.y; dst[i*4+2]=(bf16)v.z; dst[i*4+3]=(bf16)v.w;
            }
        }
        {
            int node = m0 + arow; int nc = node < N ? node : N - 1;
            long long g = (j == 0) ? (long long)nc : (long long)nbr[(long long)nc * 4 + (j - 1)];
            const float4* src = (const float4*)(x + g * FIN);
            #pragma unroll
            for (int i = 0; i < 8; ++i) {
                int c4 = asub + i * 4;
                float4 v = src[c4];
                bf16* dst = &As[arow][c4 * 4];
                dst[0]=(bf16)v.x; dst[1]=(bf16)v.y; dst[2]=(bf16)v.z; dst[3]=(bf16)v.w;
            }
        }
        __syncthreads();
        #pragma unroll
        for (int kk = 0; kk < 4; ++kk) {
            bf16x8 a = *(const bf16x8*)&As[wave * 16 + l16][kk * 32 + quad * 8];
            #pragma unroll
            for (int nt = 0; nt < 8; ++nt) {
                bf16x8 b = *(const bf16x8*)&Bs[nt * 16 + l16][kk * 32 + quad * 8];
                acc[nt] = __builtin_amdgcn_mfma_f32_16x16x32_bf16(a, b, acc[nt], 0, 0, 0);
            }
        }
        __syncthreads();
    }
    const int m_local = wave * 16 + quad * 4;
    #pragma unroll
    for (int nt = 0; nt < 8; ++nt) {
        int n = nt * 16 + l16;
        float bvv = bias[n];
        #pragma unroll
        for (int r = 0; r < 4; ++r) {
            int node = m0 + m_local + r;
            if (node < N) out[(long)node * FOUT + n] = acc[nt][r] + bvv;
        }
    }
}

extern "C" void kernel_launch(void* const* d_in, const int* in_sizes, int n_in,
                              void* d_out, int out_size, void* d_ws, size_t ws_size,
                              hipStream_t stream) {
    const float* x    = (const float*)d_in[0];
    const int*   nbr  = (const int*)d_in[1];
    const float* W    = (const float*)d_in[2];
    const float* bias = (const float*)d_in[3];
    float* out = (float*)d_out;

    int N = in_sizes[0] / FIN;                              // 200000
    size_t xb_bytes = (size_t)N * FIN * sizeof(bf16);       // 51.2 MB
    size_t wb_bytes = (size_t)FOUT * FANIN * sizeof(bf16);  // 160 KB

    if (ws_size >= xb_bytes + wb_bytes) {
        bf16* xb = (bf16*)d_ws;
        bf16* wb = (bf16*)((char*)d_ws + xb_bytes);
        long nx4   = (long)N * FIN / 4;
        long ntot4 = nx4 + (long)FOUT * FANIN / 4;
        int cgrid = (int)((ntot4 + 255) / 256);
        convert_kernel<<<cgrid, 256, 0, stream>>>(x, W, xb, wb, nx4, ntot4);
        int grid = (N + BM - 1) / BM;                       // 1563
        mcc_mfma<<<grid, 256, 0, stream>>>(xb, nbr, wb, bias, out, N);
    } else {
        int grid = (N + FBM - 1) / FBM;
        mcc_fallback<<<grid, 256, 0, stream>>>(x, nbr, W, bias, out, N);
    }
}